// Round 13
// baseline (470.330 us; speedup 1.0000x reference)
//
#include <hip/hip_runtime.h>

#define D 128
#define NH 8
#define CH 16
#define NEG 0.2f
#define BN_EPS 1e-5f
#define MAXDEG 32
#define NSLICE 32
#define WROWS 144            // 128 weight cols + 16 score cols

typedef unsigned int uint;
typedef unsigned short ushort;
typedef __attribute__((ext_vector_type(8))) short bfrag;
typedef __attribute__((ext_vector_type(4))) float ffrag;

__device__ __forceinline__ float bf_lo(uint u){ return __uint_as_float(u << 16); }
__device__ __forceinline__ float bf_hi(uint u){ return __uint_as_float(u & 0xffff0000u); }
__device__ __forceinline__ float bf2f(ushort s){ return __uint_as_float(((uint)s) << 16); }
__device__ __forceinline__ ushort f2b(float f){
  uint u = __float_as_uint(f);
  u += 0x7fffu + ((u >> 16) & 1u);      // round-to-nearest-even
  return (ushort)(u >> 16);
}

// ---------------- CSR build: compact 8-slot rows + overflow ----------------
__global__ void k_scatter(const int* __restrict__ ei, int* __restrict__ deg,
                          int* __restrict__ col8, int* __restrict__ colOv, int E){
  int e = blockIdx.x*blockDim.x + threadIdx.x;
  if (e < E){
    int d = ei[E + e];
    int pos = atomicAdd(&deg[d], 1);
    if (pos < 8) col8[d*8 + pos] = ei[e];
    else if (pos < MAXDEG) colOv[d*24 + pos - 8] = ei[e];
  }
}

// ---------------- fused setup: init | gbound | wprep | wsc | pack ----------------
__global__ void k_setup(const float* __restrict__ x, const float* __restrict__ Wp,
                        const float* __restrict__ bp, ushort* __restrict__ h,
                        const int* __restrict__ batch, int* __restrict__ gs,
                        const float* __restrict__ Wg, const float* __restrict__ asrc,
                        const float* __restrict__ adst, ushort* __restrict__ WtB,
                        const int* __restrict__ deg, int* __restrict__ col8,
                        int n, int G, int WTOT, int bInit, int bGb, int bWp, int bWsc){
  int bid = blockIdx.x;
  int t = threadIdx.x;
  if (bid < bInit){
    int i = bid*256 + t;
    if (i >= n*32) return;
    int nid = i >> 5, d4 = (i & 31)*4;
    const float* xr = x + nid*16;
    float s[4] = { bp[d4], bp[d4+1], bp[d4+2], bp[d4+3] };
#pragma unroll
    for (int k = 0; k < 16; k++){
      float xv = xr[k];
      const float* wr = Wp + k*D + d4;
      s[0] += xv*wr[0]; s[1] += xv*wr[1]; s[2] += xv*wr[2]; s[3] += xv*wr[3];
    }
    uint2 o;
    o.x = ((uint)f2b(fmaxf(s[0],0.f))) | (((uint)f2b(fmaxf(s[1],0.f))) << 16);
    o.y = ((uint)f2b(fmaxf(s[2],0.f))) | (((uint)f2b(fmaxf(s[3],0.f))) << 16);
    *(uint2*)(h + (size_t)nid*D + d4) = o;
  } else if (bid < bInit + bGb){
    int i = (bid - bInit)*256 + t;
    if (i >= n) return;
    int b = batch[i];
    int bpv = (i == 0) ? -1 : batch[i-1];
    for (int g = bpv + 1; g <= b; g++) gs[g] = i;
    if (i == n-1) for (int g = b + 1; g <= G; g++) gs[g] = n;
  } else if (bid < bInit + bGb + bWp){
    int i = (bid - bInit - bGb)*256 + t;
    if (i >= WTOT) return;
    int l = i >> 14, r = i & 16383, nn = r >> 7, kk = r & 127;
    WtB[(size_t)l*WROWS*D + nn*D + kk] = f2b(Wg[(size_t)l*16384 + kk*128 + nn]);
  } else if (bid < bInit + bGb + bWp + bWsc){
    int i = (bid - bInit - bGb - bWp)*256 + t;
    int wscTot = (WTOT >> 14)*16*128;     // L*16*128
    if (i >= wscTot) return;
    int l = i >> 11, r = i & 2047, j = r >> 7, k = r & 127;
    const float* wrow = Wg + (size_t)l*16384 + k*128;
    float s = 0.f;
    if (j < 8){
      const float* av = asrc + l*128 + j*16;
#pragma unroll
      for (int c = 0; c < 16; c++) s += wrow[j*16 + c] * av[c];
    } else {
      const float* av = adst + l*128 + (j - 8)*16;
#pragma unroll
      for (int c = 0; c < 16; c++) s += wrow[(j - 8)*16 + c] * av[c];
    }
    WtB[(size_t)l*WROWS*D + (128 + j)*D + k] = f2b(s);
  } else {
    // pack deg (clamped) into col8[d*8] bits [24:31]; ids < 2^17
    int i = (bid - bInit - bGb - bWp - bWsc)*256 + t;
    if (i >= n) return;
    int dg = deg[i]; if (dg > MAXDEG) dg = MAXDEG;
    col8[i*8] = (col8[i*8] & 0x00FFFFFF) | (dg << 24);
  }
}

// ---------------- MFMA bf16 GEMM 128x144: register-only A-path ----------------
__global__ __launch_bounds__(256) void k_gemm(const ushort* __restrict__ hin,
                                              const ushort* __restrict__ WtB,
                                              ushort* __restrict__ xh,
                                              float* __restrict__ sc2,
                                              const float* __restrict__ bnsum,
                                              const float* __restrict__ gamma,
                                              const float* __restrict__ beta,
                                              int n, int first){
  __shared__ __align__(16) ushort oL[128*136];   // C repack, stride 136
  __shared__ float sS[128], sB[128];
  int t = threadIdx.x;
  int wid = t >> 6, lane = t & 63, l15 = lane & 15, quad = lane >> 4;
  int n0 = blockIdx.x * 128;
  int rbase = wid*32;                  // wave-private row base

  if (t < 128){
    float sc, sh;
    if (first){ sc = 1.f; sh = 0.f; }
    else {
      float s = 0.f, s2 = 0.f;
#pragma unroll 8
      for (int sl = 0; sl < NSLICE; sl++){
        s  += bnsum[sl*256 + t];
        s2 += bnsum[sl*256 + 128 + t];
      }
      float invn = 1.0f / (float)n;
      float mu = s * invn;
      float var = s2 * invn - mu*mu;
      sc = gamma[t] * rsqrtf(var + BN_EPS);
      sh = beta[t] - mu*sc;
    }
    sS[t] = sc; sB[t] = sh;
  }
  __syncthreads();   // the only barrier

  // A fragments: direct global load (16B, aligned), BN+ReLU in registers
  bfrag a[2][4];
#pragma unroll
  for (int mt = 0; mt < 2; mt++){
    int row = n0 + rbase + mt*16 + l15;
#pragma unroll
    for (int ks = 0; ks < 4; ks++){
      union { bfrag b; ushort us[8]; } in, ov;
      in.b = (bfrag){0,0,0,0,0,0,0,0};
      if (row < n) in.b = *(const bfrag*)(hin + (size_t)row*D + ks*32 + quad*8);
      int kb = ks*32 + quad*8;
#pragma unroll
      for (int j = 0; j < 8; j++){
        float f = bf2f(in.us[j])*sS[kb + j] + sB[kb + j];
        ov.us[j] = f2b(f > 0.f ? f : 0.f);
      }
      a[mt][ks] = ov.b;
    }
  }

  ffrag acc[2][9];
#pragma unroll
  for (int mt = 0; mt < 2; mt++)
#pragma unroll
    for (int nt = 0; nt < 9; nt++) acc[mt][nt] = (ffrag){0.f,0.f,0.f,0.f};

  // MFMA with direct-global B (L2-hot); nt==8 is the score-column tile
#pragma unroll
  for (int nt = 0; nt < 9; nt++){
#pragma unroll
    for (int ks = 0; ks < 4; ks++){
      bfrag b = *(const bfrag*)(WtB + (size_t)(nt*16 + l15)*D + ks*32 + quad*8);
      acc[0][nt] = __builtin_amdgcn_mfma_f32_16x16x32_bf16(a[0][ks], b, acc[0][nt], 0, 0, 0);
      acc[1][nt] = __builtin_amdgcn_mfma_f32_16x16x32_bf16(a[1][ks], b, acc[1][nt], 0, 0, 0);
    }
  }

  // store scores (fp32, C-layout direct): sc2[row][l15]
#pragma unroll
  for (int mt = 0; mt < 2; mt++)
#pragma unroll
    for (int r = 0; r < 4; r++){
      int grow = n0 + rbase + mt*16 + quad*4 + r;
      if (grow < n) sc2[(size_t)grow*16 + l15] = acc[mt][8][r];
    }

  // repack C into wave-private rows of oL (no barrier needed)
#pragma unroll
  for (int mt = 0; mt < 2; mt++)
#pragma unroll
    for (int nt = 0; nt < 8; nt++)
#pragma unroll
      for (int r = 0; r < 4; r++){
        int row = rbase + mt*16 + quad*4 + r;
        oL[row*136 + nt*16 + l15] = f2b(acc[mt][nt][r]);
      }

  // store xh: wave-private 32 rows x 16 uint4
#pragma unroll
  for (int i = 0; i < 8; i++){
    int lin = i*64 + lane;
    int r = rbase + (lin >> 4), c8 = lin & 15;
    int grow = n0 + r;
    if (grow < n)
      *(uint4*)(xh + (size_t)grow*D + c8*8) = *(const uint4*)(oL + r*136 + c8*8);
  }
}

// ---------------- aggregation: 2 nodes/wave, 32 lanes/node, 4 channels/lane ----------------
// Lane l: half = l>>5 selects node, w = l&31, channels 4w..4w+3 (uint2), head hc = w>>2.
// Halves the per-node exp/score/addressing work and VMEM instruction count vs 1 node/wave.
__global__ __launch_bounds__(1024) void k_agg(const uint* __restrict__ xh32,
                                              const float* __restrict__ sc2,
                                              const int* __restrict__ col8,
                                              const int* __restrict__ colOv,
                                              const float* __restrict__ bg,
                                              ushort* __restrict__ hout,
                                              float* __restrict__ bnsum, int n){
  int wv = threadIdx.x >> 6;
  int l  = threadIdx.x & 63;
  int half = l >> 5;
  int w = l & 31;
  int hc = w >> 2;          // head (4 lanes per head)
  int nid = blockIdx.x*32 + wv*2 + half;

  float so[4] = {0.f,0.f,0.f,0.f}, qo[4] = {0.f,0.f,0.f,0.f};

  if (nid < n){
    // ---- epoch 1: packed col row (32B) + self loads ----
    const int4* c8p = (const int4*)(col8 + nid*8);
    int4 ca = c8p[0], cb4 = c8p[1];
    float ad = sc2[nid*16 + 8 + hc];
    float as = sc2[nid*16 + hc];
    uint2 selfv = *((const uint2*)(xh32 + nid*64) + w);
    int cnt = ((uint)ca.x) >> 24;
    int idx[8];
    idx[0] = ca.x & 0x00FFFFFF; idx[1] = ca.y; idx[2] = ca.z; idx[3] = ca.w;
    idx[4] = cb4.x; idx[5] = cb4.y; idx[6] = cb4.z; idx[7] = cb4.w;
    // ---- epoch 2: score gathers + row gathers (uint2: 32 lanes = full row) ----
    float av[8]; uint2 xv[8];
#pragma unroll
    for (int jj = 0; jj < 8; jj++){
      av[jj] = sc2[idx[jj]*16 + hc];
      xv[jj] = *((const uint2*)(xh32 + idx[jj]*64) + w);
    }
    int cc = cnt < 8 ? cnt : 8;
    // ---- shuffle-free softmax accumulate ----
    float e0 = as + ad; e0 = e0 > 0.f ? e0 : NEG*e0;
    float w0 = __expf(e0);
    float dnm = w0;
    float acc[4] = { w0*bf_lo(selfv.x), w0*bf_hi(selfv.x),
                     w0*bf_lo(selfv.y), w0*bf_hi(selfv.y) };
#pragma unroll
    for (int jj = 0; jj < 8; jj++){
      float e = av[jj] + ad; e = e > 0.f ? e : NEG*e;
      float wg = (jj < cc) ? __expf(e) : 0.f;
      dnm += wg;
      acc[0] += wg * bf_lo(xv[jj].x); acc[1] += wg * bf_hi(xv[jj].x);
      acc[2] += wg * bf_lo(xv[jj].y); acc[3] += wg * bf_hi(xv[jj].y);
    }
    // ---- rare tail: deg > 8 ----
    for (int c0 = 8; c0 < cnt; c0 += 8){
      int cc2 = cnt - c0; if (cc2 > 8) cc2 = 8;
#pragma unroll
      for (int jj = 0; jj < 8; jj++)
        idx[jj] = (jj < cc2) ? colOv[nid*24 + c0 - 8 + jj] : 0;
#pragma unroll
      for (int jj = 0; jj < 8; jj++){
        av[jj] = sc2[idx[jj]*16 + hc];
        xv[jj] = *((const uint2*)(xh32 + idx[jj]*64) + w);
      }
#pragma unroll
      for (int jj = 0; jj < 8; jj++){
        float e = av[jj] + ad; e = e > 0.f ? e : NEG*e;
        float wg = (jj < cc2) ? __expf(e) : 0.f;
        dnm += wg;
        acc[0] += wg * bf_lo(xv[jj].x); acc[1] += wg * bf_hi(xv[jj].x);
        acc[2] += wg * bf_lo(xv[jj].y); acc[3] += wg * bf_hi(xv[jj].y);
      }
    }
    float inv = 1.0f / dnm;
    float4 bgv = *(const float4*)(bg + w*4);
    float o0 = acc[0]*inv + bgv.x, o1 = acc[1]*inv + bgv.y;
    float o2 = acc[2]*inv + bgv.z, o3 = acc[3]*inv + bgv.w;
    uint2 po;
    po.x = ((uint)f2b(o0)) | (((uint)f2b(o1)) << 16);
    po.y = ((uint)f2b(o2)) | (((uint)f2b(o3)) << 16);
    *((uint2*)hout + nid*32 + w) = po;
    so[0] = o0; so[1] = o1; so[2] = o2; so[3] = o3;
    qo[0] = o0*o0; qo[1] = o1*o1; qo[2] = o2*o2; qo[3] = o3*o3;
  }

  // combine the two half-waves (same channels, different nodes) via xor-32
#pragma unroll
  for (int j = 0; j < 4; j++){
    so[j] += __shfl_xor(so[j], 32);
    qo[j] += __shfl_xor(qo[j], 32);
  }
  __shared__ float red[16][32][8];
  if (half == 0){
#pragma unroll
    for (int j = 0; j < 4; j++){ red[wv][w][j] = so[j]; red[wv][w][4 + j] = qo[j]; }
  }
  __syncthreads();
  if (threadIdx.x < 256){
    int t = threadIdx.x;
    int ww = t >> 3, j = t & 7;
    float tot = 0.f;
#pragma unroll
    for (int k = 0; k < 16; k++) tot += red[k][ww][j];
    int c = ww*4 + (j & 3);
    float* bs = bnsum + (blockIdx.x & (NSLICE - 1))*256;
    atomicAdd(&bs[(j < 4) ? c : (128 + c)], tot);
  }
}

// ---------------- fused pool (BN+ReLU) + output heads ----------------
__global__ __launch_bounds__(128) void k_poolheads(const ushort* __restrict__ h,
                                                   const int* __restrict__ gs,
                                                   const float* __restrict__ bnsum,
                                                   const float* __restrict__ gamma,
                                                   const float* __restrict__ beta,
                                                   const float* __restrict__ hW1,
                                                   const float* __restrict__ hb1,
                                                   const float* __restrict__ hW2,
                                                   const float* __restrict__ hb2,
                                                   float* __restrict__ out, int n){
  int g = blockIdx.x;
  int t = threadIdx.x;
  __shared__ float sp[128];
  int st = gs[g], en = gs[g + 1];
  float sm = 0.f, s2 = 0.f;
#pragma unroll 8
  for (int sl = 0; sl < NSLICE; sl++){
    sm += bnsum[sl*256 + t];
    s2 += bnsum[sl*256 + 128 + t];
  }
  float invn = 1.0f / (float)n;
  float mu = sm * invn;
  float var = s2 * invn - mu*mu;
  float sc = gamma[t] * rsqrtf(var + BN_EPS);
  float sh = beta[t] - mu*sc;
  float s = 0.f;
  for (int r = st; r < en; r++){
    float v = bf2f(h[(size_t)r*D + t]) * sc + sh;
    s += v > 0.f ? v : 0.f;
  }
  float cnt = (float)(en - st);
  sp[t] = s / fmaxf(cnt, 1.0f);
  __syncthreads();
  int wv = t >> 6, m = t & 63;
  for (int k = wv; k < 3; k += 2){
    float acc = hb1[k*64 + m];
    const float* w = hW1 + k*8192 + m;      // [d][m], coalesced over m
#pragma unroll 16
    for (int d = 0; d < 128; d++) acc += sp[d] * w[d*64];
    float val = fmaxf(acc, 0.f) * hW2[k*64 + m];
#pragma unroll
    for (int off = 32; off; off >>= 1) val += __shfl_down(val, off);
    if (m == 0) out[(size_t)g*3 + k] = val + hb2[k];
  }
}

// ---------------- launch ----------------
extern "C" void kernel_launch(void* const* d_in, const int* in_sizes, int n_in,
                              void* d_out, int out_size, void* d_ws, size_t ws_size,
                              hipStream_t stream){
  const float* x    = (const float*)d_in[0];
  const int*   ei   = (const int*)d_in[1];
  const int*   batch= (const int*)d_in[2];
  const float* Wp   = (const float*)d_in[3];
  const float* bp   = (const float*)d_in[4];
  const float* Wg   = (const float*)d_in[5];
  const float* asrc = (const float*)d_in[6];
  const float* adst = (const float*)d_in[7];
  const float* bg   = (const float*)d_in[8];
  const float* gamma= (const float*)d_in[9];
  const float* beta = (const float*)d_in[10];
  const float* hW1  = (const float*)d_in[11];
  const float* hb1  = (const float*)d_in[12];
  const float* hW2  = (const float*)d_in[13];
  const float* hb2  = (const float*)d_in[14];
  float* out = (float*)d_out;

  const int E = in_sizes[1] / 2;
  const int N = in_sizes[2];
  const int G = out_size / 3;
  const int WTOT = in_sizes[5];           // L*D*D
  const int L = WTOT / 16384;

  char* w = (char*)d_ws;
  auto alloc = [&](size_t bytes){ char* p = w; w += (bytes + 255) & ~(size_t)255; return p; };
  ushort* h     = (ushort*)alloc((size_t)N*D*2);
  ushort* xh    = (ushort*)alloc((size_t)N*D*2);
  float* sc2    = (float*)alloc((size_t)N*16*4);
  // zero-initialized region: deg, col8, colOv, bnsumL contiguous
  int*   deg    = (int*)  alloc((size_t)N*4);
  int*   col8   = (int*)  alloc((size_t)N*8*4);
  int*   colOv  = (int*)  alloc((size_t)N*24*4);
  float* bnsumL = (float*)alloc((size_t)4*NSLICE*256*4);   // per-layer slices
  char*  zend   = w;
  int*   gs     = (int*)  alloc((size_t)(G + 1)*4);
  ushort* WtB   = (ushort*)alloc((size_t)L*WROWS*D*2);

  hipMemsetAsync(deg, 0, (size_t)(zend - (char*)deg), stream);
  k_scatter<<<(E + 255)/256, 256, 0, stream>>>(ei, deg, col8, colOv, E);

  const int bInit = (N*32 + 255)/256;
  const int bGb   = (N + 255)/256;
  const int bWp   = (WTOT + 255)/256;
  const int bWsc  = (WTOT/8 + 255)/256;   // L*16*128 elements
  const int bPack = (N + 255)/256;
  k_setup<<<bInit + bGb + bWp + bWsc + bPack, 256, 0, stream>>>(
      x, Wp, bp, h, batch, gs, Wg, asrc, adst, WtB, deg, col8,
      N, G, WTOT, bInit, bGb, bWp, bWsc);

  for (int l = 0; l < 4; l++){
    float* bnPrev = bnsumL + (size_t)(l - 1)*NSLICE*256;   // unused when l==0
    float* bnCur  = bnsumL + (size_t)l*NSLICE*256;
    k_gemm<<<(N + 127)/128, 256, 0, stream>>>(h, WtB + (size_t)l*WROWS*D, xh, sc2,
                                              l == 0 ? bnCur : bnPrev,
                                              gamma + l*D, beta + l*D, N, l == 0);
    k_agg<<<(N + 31)/32, 1024, 0, stream>>>((const uint*)xh, sc2, col8, colOv,
                                            bg + l*D, h, bnCur, N);
  }

  k_poolheads<<<G, 128, 0, stream>>>(h, gs, bnsumL + (size_t)3*NSLICE*256,
                                     gamma + 3*D, beta + 3*D,
                                     hW1, hb1, hW2, hb2, out, N);
}

// Round 14
// 456.133 us; speedup vs baseline: 1.0311x; 1.0311x over previous
//
#include <hip/hip_runtime.h>

#define D 128
#define NH 8
#define CH 16
#define NEG 0.2f
#define BN_EPS 1e-5f
#define MAXDEG 32
#define NSLICE 32
#define WROWS 144            // 128 weight cols + 16 score cols

typedef unsigned int uint;
typedef unsigned short ushort;
typedef __attribute__((ext_vector_type(8))) short bfrag;
typedef __attribute__((ext_vector_type(4))) float ffrag;

__device__ __forceinline__ float bf_lo(uint u){ return __uint_as_float(u << 16); }
__device__ __forceinline__ float bf_hi(uint u){ return __uint_as_float(u & 0xffff0000u); }
__device__ __forceinline__ float bf2f(ushort s){ return __uint_as_float(((uint)s) << 16); }
__device__ __forceinline__ ushort f2b(float f){
  uint u = __float_as_uint(f);
  u += 0x7fffu + ((u >> 16) & 1u);      // round-to-nearest-even
  return (ushort)(u >> 16);
}

// ---------------- CSR build: row-major slotted scatter (col pre-zeroed) ----------------
__global__ void k_scatter(const int* __restrict__ ei, int* __restrict__ deg,
                          int* __restrict__ col, int E){
  int e = blockIdx.x*blockDim.x + threadIdx.x;
  if (e < E){
    int d = ei[E + e];
    int pos = atomicAdd(&deg[d], 1);
    if (pos < MAXDEG) col[(size_t)d*MAXDEG + pos] = ei[e];
  }
}

// ---------------- fused setup: init | gbound | wprep | wsc ----------------
__global__ void k_setup(const float* __restrict__ x, const float* __restrict__ Wp,
                        const float* __restrict__ bp, ushort* __restrict__ h,
                        const int* __restrict__ batch, int* __restrict__ gs,
                        const float* __restrict__ Wg, const float* __restrict__ asrc,
                        const float* __restrict__ adst, ushort* __restrict__ WtB,
                        int n, int G, int WTOT, int bInit, int bGb, int bWp){
  int bid = blockIdx.x;
  int t = threadIdx.x;
  if (bid < bInit){
    int i = bid*256 + t;
    if (i >= n*32) return;
    int nid = i >> 5, d4 = (i & 31)*4;
    const float* xr = x + nid*16;
    float s[4] = { bp[d4], bp[d4+1], bp[d4+2], bp[d4+3] };
#pragma unroll
    for (int k = 0; k < 16; k++){
      float xv = xr[k];
      const float* wr = Wp + k*D + d4;
      s[0] += xv*wr[0]; s[1] += xv*wr[1]; s[2] += xv*wr[2]; s[3] += xv*wr[3];
    }
    uint2 o;
    o.x = ((uint)f2b(fmaxf(s[0],0.f))) | (((uint)f2b(fmaxf(s[1],0.f))) << 16);
    o.y = ((uint)f2b(fmaxf(s[2],0.f))) | (((uint)f2b(fmaxf(s[3],0.f))) << 16);
    *(uint2*)(h + (size_t)nid*D + d4) = o;
  } else if (bid < bInit + bGb){
    int i = (bid - bInit)*256 + t;
    if (i >= n) return;
    int b = batch[i];
    int bpv = (i == 0) ? -1 : batch[i-1];
    for (int g = bpv + 1; g <= b; g++) gs[g] = i;
    if (i == n-1) for (int g = b + 1; g <= G; g++) gs[g] = n;
  } else if (bid < bInit + bGb + bWp){
    int i = (bid - bInit - bGb)*256 + t;
    if (i >= WTOT) return;
    int l = i >> 14, r = i & 16383, nn = r >> 7, kk = r & 127;
    WtB[(size_t)l*WROWS*D + nn*D + kk] = f2b(Wg[(size_t)l*16384 + kk*128 + nn]);
  } else {
    int i = (bid - bInit - bGb - bWp)*256 + t;
    int wscTot = (WTOT >> 14)*16*128;     // L*16*128
    if (i >= wscTot) return;
    int l = i >> 11, r = i & 2047, j = r >> 7, k = r & 127;
    const float* wrow = Wg + (size_t)l*16384 + k*128;
    float s = 0.f;
    if (j < 8){
      const float* av = asrc + l*128 + j*16;
#pragma unroll
      for (int c = 0; c < 16; c++) s += wrow[j*16 + c] * av[c];
    } else {
      const float* av = adst + l*128 + (j - 8)*16;
#pragma unroll
      for (int c = 0; c < 16; c++) s += wrow[(j - 8)*16 + c] * av[c];
    }
    WtB[(size_t)l*WROWS*D + (128 + j)*D + k] = f2b(s);
  }
}

// ---------------- MFMA bf16 GEMM 128x144: register-only A-path, no-LDS epilogue ----------------
// A fragments direct from global (fragment layout == contiguous 16B); BN+ReLU in
// registers; C stored directly to global in C-layout (scalar bf16 stores,
// write-combined in L2). LDS is just the 1 KB BN scale/shift broadcast.
__global__ __launch_bounds__(256) void k_gemm(const ushort* __restrict__ hin,
                                              const ushort* __restrict__ WtB,
                                              ushort* __restrict__ xh,
                                              float* __restrict__ sc2,
                                              const float* __restrict__ bnsum,
                                              const float* __restrict__ gamma,
                                              const float* __restrict__ beta,
                                              int n, int first){
  __shared__ float sS[128], sB[128];
  int t = threadIdx.x;
  int wid = t >> 6, lane = t & 63, l15 = lane & 15, quad = lane >> 4;
  int n0 = blockIdx.x * 128;
  int rbase = wid*32;                  // wave-private row base

  if (t < 128){
    float sc, sh;
    if (first){ sc = 1.f; sh = 0.f; }
    else {
      float s = 0.f, s2 = 0.f;
#pragma unroll 8
      for (int sl = 0; sl < NSLICE; sl++){
        s  += bnsum[sl*256 + t];
        s2 += bnsum[sl*256 + 128 + t];
      }
      float invn = 1.0f / (float)n;
      float mu = s * invn;
      float var = s2 * invn - mu*mu;
      sc = gamma[t] * rsqrtf(var + BN_EPS);
      sh = beta[t] - mu*sc;
    }
    sS[t] = sc; sB[t] = sh;
  }
  __syncthreads();   // the only barrier

  // A fragments: direct global load (16B, aligned), BN+ReLU in registers
  bfrag a[2][4];
#pragma unroll
  for (int mt = 0; mt < 2; mt++){
    int row = n0 + rbase + mt*16 + l15;
#pragma unroll
    for (int ks = 0; ks < 4; ks++){
      union { bfrag b; ushort us[8]; } in, ov;
      in.b = (bfrag){0,0,0,0,0,0,0,0};
      if (row < n) in.b = *(const bfrag*)(hin + (size_t)row*D + ks*32 + quad*8);
      int kb = ks*32 + quad*8;
#pragma unroll
      for (int j = 0; j < 8; j++){
        float f = bf2f(in.us[j])*sS[kb + j] + sB[kb + j];
        ov.us[j] = f2b(f > 0.f ? f : 0.f);
      }
      a[mt][ks] = ov.b;
    }
  }

  ffrag acc[2][9];
#pragma unroll
  for (int mt = 0; mt < 2; mt++)
#pragma unroll
    for (int nt = 0; nt < 9; nt++) acc[mt][nt] = (ffrag){0.f,0.f,0.f,0.f};

  // MFMA with direct-global B (L2-hot); nt==8 is the score-column tile
#pragma unroll
  for (int nt = 0; nt < 9; nt++){
#pragma unroll
    for (int ks = 0; ks < 4; ks++){
      bfrag b = *(const bfrag*)(WtB + (size_t)(nt*16 + l15)*D + ks*32 + quad*8);
      acc[0][nt] = __builtin_amdgcn_mfma_f32_16x16x32_bf16(a[0][ks], b, acc[0][nt], 0, 0, 0);
      acc[1][nt] = __builtin_amdgcn_mfma_f32_16x16x32_bf16(a[1][ks], b, acc[1][nt], 0, 0, 0);
    }
  }

  // epilogue: direct stores, no LDS. C mapping: row = rbase+mt*16+quad*4+r, col = nt*16+l15.
#pragma unroll
  for (int mt = 0; mt < 2; mt++)
#pragma unroll
    for (int r = 0; r < 4; r++){
      int grow = n0 + rbase + mt*16 + quad*4 + r;
      if (grow < n){
        sc2[(size_t)grow*16 + l15] = acc[mt][8][r];
        ushort* xr = xh + (size_t)grow*D + l15;
#pragma unroll
        for (int nt = 0; nt < 8; nt++)
          xr[nt*16] = f2b(acc[mt][nt][r]);
      }
    }
}

// ---------------- wave-per-node aggregation (R10 measured-best form) ----------------
__global__ __launch_bounds__(1024) void k_agg(const uint* __restrict__ xh32,
                                              const float* __restrict__ sc2,
                                              const int* __restrict__ deg,
                                              const int* __restrict__ col,
                                              const float* __restrict__ bg,
                                              ushort* __restrict__ hout,
                                              float* __restrict__ bnsum, int n){
  int wv = threadIdx.x >> 6;
  int l  = threadIdx.x & 63;
  int hs = l & 7;
  int jc = l >> 3;          // score-role edge slot AND channel-role head
  int nid = blockIdx.x*16 + wv;

  float s0=0.f, s1=0.f, q0=0.f, q1=0.f;

  if (nid < n){
    const int* cb = col + nid*MAXDEG;
    // ---- epoch 1: ALL independent loads (deg, col[0..7], scores, self row) ----
    int cnt = deg[nid];
    int idx[8];
#pragma unroll
    for (int jj = 0; jj < 8; jj++) idx[jj] = cb[jj];      // col pre-zeroed, unconditional
    float ad = sc2[nid*16 + 8 + hs];
    float as = sc2[nid*16 + hs];
    uint selfv = xh32[nid*64 + l];
    // ---- epoch 2: gathers (addresses from epoch 1 only) ----
    float av = sc2[idx[jc]*16 + hs];
    float xv0[8], xv1[8];
#pragma unroll
    for (int jj = 0; jj < 8; jj++){
      uint v = xh32[idx[jj]*64 + l];
      xv0[jj] = bf_lo(v); xv1[jj] = bf_hi(v);
    }
    if (cnt > MAXDEG) cnt = MAXDEG;
    int cc = cnt < 8 ? cnt : 8;
    // ---- compute chunk 0 ----
    float e0 = as + ad; e0 = e0 > 0.f ? e0 : NEG*e0;
    float m = e0, dnm = 1.f;
    float acc0 = bf_lo(selfv), acc1 = bf_hi(selfv);

    float e = -1e30f;
    if (jc < cc){ float ee = av + ad; e = ee > 0.f ? ee : NEG*ee; }
    float mc = e;
    mc = fmaxf(mc, __shfl_xor(mc, 8));
    mc = fmaxf(mc, __shfl_xor(mc, 16));
    mc = fmaxf(mc, __shfl_xor(mc, 32));
    float mn = fmaxf(m, mc);
    float rsc = __expf(m - mn);
    float w = (jc < cc) ? __expf(e - mn) : 0.f;
    float ws = w;
    ws += __shfl_xor(ws, 8);
    ws += __shfl_xor(ws, 16);
    ws += __shfl_xor(ws, 32);
    dnm = dnm*rsc + ws;
    m = mn;
    float rc = __shfl(rsc, jc);
    acc0 *= rc; acc1 *= rc;
#pragma unroll
    for (int jj = 0; jj < 8; jj++){
      float wj = __shfl(w, jj*8 + jc);
      acc0 += wj * xv0[jj];
      acc1 += wj * xv1[jj];
    }
    // ---- rare tail: deg > 8 ----
    for (int c0 = 8; c0 < cnt; c0 += 8){
      int cc2 = cnt - c0; if (cc2 > 8) cc2 = 8;
#pragma unroll
      for (int jj = 0; jj < 8; jj++) idx[jj] = cb[c0 + jj];
      float av2 = sc2[idx[jc]*16 + hs];
#pragma unroll
      for (int jj = 0; jj < 8; jj++){
        uint v = xh32[idx[jj]*64 + l];
        xv0[jj] = bf_lo(v); xv1[jj] = bf_hi(v);
      }
      float e2 = -1e30f;
      if (jc < cc2){ float ee = av2 + ad; e2 = ee > 0.f ? ee : NEG*ee; }
      float mc2 = e2;
      mc2 = fmaxf(mc2, __shfl_xor(mc2, 8));
      mc2 = fmaxf(mc2, __shfl_xor(mc2, 16));
      mc2 = fmaxf(mc2, __shfl_xor(mc2, 32));
      float mn2 = fmaxf(m, mc2);
      float rsc2 = __expf(m - mn2);
      float w2 = (jc < cc2) ? __expf(e2 - mn2) : 0.f;
      float ws2 = w2;
      ws2 += __shfl_xor(ws2, 8);
      ws2 += __shfl_xor(ws2, 16);
      ws2 += __shfl_xor(ws2, 32);
      dnm = dnm*rsc2 + ws2;
      m = mn2;
      float rc2 = __shfl(rsc2, jc);
      acc0 *= rc2; acc1 *= rc2;
#pragma unroll
      for (int jj = 0; jj < 8; jj++){
        float wj = __shfl(w2, jj*8 + jc);
        acc0 += wj * xv0[jj];
        acc1 += wj * xv1[jj];
      }
    }
    float df = __shfl(dnm, jc);
    float inv = 1.0f / df;
    float b0 = bg[2*l], b1 = bg[2*l + 1];
    float o0 = acc0*inv + b0, o1 = acc1*inv + b1;
    uint p = ((uint)f2b(o0)) | (((uint)f2b(o1)) << 16);
    ((uint*)hout)[nid*64 + l] = p;
    s0 = o0; s1 = o1; q0 = o0*o0; q1 = o1*o1;
  }

  // fused BN stats: 16-wave LDS reduce, one sliced atomic set per block
  __shared__ float red[16][64][4];
  red[wv][l][0] = s0; red[wv][l][1] = s1; red[wv][l][2] = q0; red[wv][l][3] = q1;
  __syncthreads();
  if (wv == 0){
    float t0 = 0.f, t1 = 0.f, t2 = 0.f, t3 = 0.f;
#pragma unroll
    for (int k = 0; k < 16; k++){
      t0 += red[k][l][0]; t1 += red[k][l][1];
      t2 += red[k][l][2]; t3 += red[k][l][3];
    }
    float* bs = bnsum + (blockIdx.x & (NSLICE - 1))*256;
    atomicAdd(&bs[2*l],       t0);
    atomicAdd(&bs[2*l + 1],   t1);
    atomicAdd(&bs[128 + 2*l], t2);
    atomicAdd(&bs[129 + 2*l], t3);
  }
}

// ---------------- fused pool (BN+ReLU) + output heads ----------------
__global__ __launch_bounds__(128) void k_poolheads(const ushort* __restrict__ h,
                                                   const int* __restrict__ gs,
                                                   const float* __restrict__ bnsum,
                                                   const float* __restrict__ gamma,
                                                   const float* __restrict__ beta,
                                                   const float* __restrict__ hW1,
                                                   const float* __restrict__ hb1,
                                                   const float* __restrict__ hW2,
                                                   const float* __restrict__ hb2,
                                                   float* __restrict__ out, int n){
  int g = blockIdx.x;
  int t = threadIdx.x;
  __shared__ float sp[128];
  int st = gs[g], en = gs[g + 1];
  float sm = 0.f, s2 = 0.f;
#pragma unroll 8
  for (int sl = 0; sl < NSLICE; sl++){
    sm += bnsum[sl*256 + t];
    s2 += bnsum[sl*256 + 128 + t];
  }
  float invn = 1.0f / (float)n;
  float mu = sm * invn;
  float var = s2 * invn - mu*mu;
  float sc = gamma[t] * rsqrtf(var + BN_EPS);
  float sh = beta[t] - mu*sc;
  float s = 0.f;
  for (int r = st; r < en; r++){
    float v = bf2f(h[(size_t)r*D + t]) * sc + sh;
    s += v > 0.f ? v : 0.f;
  }
  float cnt = (float)(en - st);
  sp[t] = s / fmaxf(cnt, 1.0f);
  __syncthreads();
  int wv = t >> 6, m = t & 63;
  for (int k = wv; k < 3; k += 2){
    float acc = hb1[k*64 + m];
    const float* w = hW1 + k*8192 + m;      // [d][m], coalesced over m
#pragma unroll 16
    for (int d = 0; d < 128; d++) acc += sp[d] * w[d*64];
    float val = fmaxf(acc, 0.f) * hW2[k*64 + m];
#pragma unroll
    for (int off = 32; off; off >>= 1) val += __shfl_down(val, off);
    if (m == 0) out[(size_t)g*3 + k] = val + hb2[k];
  }
}

// ---------------- launch ----------------
extern "C" void kernel_launch(void* const* d_in, const int* in_sizes, int n_in,
                              void* d_out, int out_size, void* d_ws, size_t ws_size,
                              hipStream_t stream){
  const float* x    = (const float*)d_in[0];
  const int*   ei   = (const int*)d_in[1];
  const int*   batch= (const int*)d_in[2];
  const float* Wp   = (const float*)d_in[3];
  const float* bp   = (const float*)d_in[4];
  const float* Wg   = (const float*)d_in[5];
  const float* asrc = (const float*)d_in[6];
  const float* adst = (const float*)d_in[7];
  const float* bg   = (const float*)d_in[8];
  const float* gamma= (const float*)d_in[9];
  const float* beta = (const float*)d_in[10];
  const float* hW1  = (const float*)d_in[11];
  const float* hb1  = (const float*)d_in[12];
  const float* hW2  = (const float*)d_in[13];
  const float* hb2  = (const float*)d_in[14];
  float* out = (float*)d_out;

  const int E = in_sizes[1] / 2;
  const int N = in_sizes[2];
  const int G = out_size / 3;
  const int WTOT = in_sizes[5];           // L*D*D
  const int L = WTOT / 16384;

  char* w = (char*)d_ws;
  auto alloc = [&](size_t bytes){ char* p = w; w += (bytes + 255) & ~(size_t)255; return p; };
  ushort* h     = (ushort*)alloc((size_t)N*D*2);
  ushort* xh    = (ushort*)alloc((size_t)N*D*2);
  float* sc2    = (float*)alloc((size_t)N*16*4);
  // zero-initialized region: deg, col, bnsumL contiguous
  int*   deg    = (int*)  alloc((size_t)N*4);
  int*   col    = (int*)  alloc(((size_t)N*MAXDEG + 64)*4);
  float* bnsumL = (float*)alloc((size_t)4*NSLICE*256*4);   // per-layer slices
  char*  zend   = w;
  int*   gs     = (int*)  alloc((size_t)(G + 1)*4);
  ushort* WtB   = (ushort*)alloc((size_t)L*WROWS*D*2);

  hipMemsetAsync(deg, 0, (size_t)(zend - (char*)deg), stream);
  k_scatter<<<(E + 255)/256, 256, 0, stream>>>(ei, deg, col, E);

  const int bInit = (N*32 + 255)/256;
  const int bGb   = (N + 255)/256;
  const int bWp   = (WTOT + 255)/256;
  const int bWsc  = (WTOT/8 + 255)/256;   // L*16*128 elements
  k_setup<<<bInit + bGb + bWp + bWsc, 256, 0, stream>>>(
      x, Wp, bp, h, batch, gs, Wg, asrc, adst, WtB,
      N, G, WTOT, bInit, bGb, bWp);

  for (int l = 0; l < 4; l++){
    float* bnPrev = bnsumL + (size_t)(l - 1)*NSLICE*256;   // unused when l==0
    float* bnCur  = bnsumL + (size_t)l*NSLICE*256;
    k_gemm<<<(N + 127)/128, 256, 0, stream>>>(h, WtB + (size_t)l*WROWS*D, xh, sc2,
                                              l == 0 ? bnCur : bnPrev,
                                              gamma + l*D, beta + l*D, N, l == 0);
    k_agg<<<(N + 15)/16, 1024, 0, stream>>>((const uint*)xh, sc2, deg, col,
                                            bg + l*D, h, bnCur, N);
  }

  k_poolheads<<<G, 128, 0, stream>>>(h, gs, bnsumL + (size_t)3*NSLICE*256,
                                     gamma + 3*D, beta + 3*D,
                                     hW1, hb1, hW2, hb2, out, N);
}

// Round 15
// 392.222 us; speedup vs baseline: 1.1991x; 1.1629x over previous
//
#include <hip/hip_runtime.h>

#define D 128
#define NH 8
#define CH 16
#define NEG 0.2f
#define BN_EPS 1e-5f
#define MAXDEG 32
#define NSLICE 32
#define WROWS 144            // 128 weight cols + 16 score cols

typedef unsigned int uint;
typedef unsigned short ushort;
typedef __attribute__((ext_vector_type(8))) short bfrag;
typedef __attribute__((ext_vector_type(4))) float ffrag;

__device__ __forceinline__ float bf_lo(uint u){ return __uint_as_float(u << 16); }
__device__ __forceinline__ float bf_hi(uint u){ return __uint_as_float(u & 0xffff0000u); }
__device__ __forceinline__ float bf2f(ushort s){ return __uint_as_float(((uint)s) << 16); }
__device__ __forceinline__ ushort f2b(float f){
  uint u = __float_as_uint(f);
  u += 0x7fffu + ((u >> 16) & 1u);      // round-to-nearest-even
  return (ushort)(u >> 16);
}

// ---------------- CSR build: row-major slotted scatter (col pre-zeroed) ----------------
__global__ void k_scatter(const int* __restrict__ ei, int* __restrict__ deg,
                          int* __restrict__ col, int E){
  int e = blockIdx.x*blockDim.x + threadIdx.x;
  if (e < E){
    int d = ei[E + e];
    int pos = atomicAdd(&deg[d], 1);
    if (pos < MAXDEG) col[(size_t)d*MAXDEG + pos] = ei[e];
  }
}

// ---------------- fused setup: init | gbound | wprep | wsc ----------------
__global__ void k_setup(const float* __restrict__ x, const float* __restrict__ Wp,
                        const float* __restrict__ bp, ushort* __restrict__ h,
                        const int* __restrict__ batch, int* __restrict__ gs,
                        const float* __restrict__ Wg, const float* __restrict__ asrc,
                        const float* __restrict__ adst, ushort* __restrict__ WtB,
                        int n, int G, int WTOT, int bInit, int bGb, int bWp){
  int bid = blockIdx.x;
  int t = threadIdx.x;
  if (bid < bInit){
    int i = bid*256 + t;
    if (i >= n*32) return;
    int nid = i >> 5, d4 = (i & 31)*4;
    const float* xr = x + nid*16;
    float s[4] = { bp[d4], bp[d4+1], bp[d4+2], bp[d4+3] };
#pragma unroll
    for (int k = 0; k < 16; k++){
      float xv = xr[k];
      const float* wr = Wp + k*D + d4;
      s[0] += xv*wr[0]; s[1] += xv*wr[1]; s[2] += xv*wr[2]; s[3] += xv*wr[3];
    }
    uint2 o;
    o.x = ((uint)f2b(fmaxf(s[0],0.f))) | (((uint)f2b(fmaxf(s[1],0.f))) << 16);
    o.y = ((uint)f2b(fmaxf(s[2],0.f))) | (((uint)f2b(fmaxf(s[3],0.f))) << 16);
    *(uint2*)(h + (size_t)nid*D + d4) = o;
  } else if (bid < bInit + bGb){
    int i = (bid - bInit)*256 + t;
    if (i >= n) return;
    int b = batch[i];
    int bpv = (i == 0) ? -1 : batch[i-1];
    for (int g = bpv + 1; g <= b; g++) gs[g] = i;
    if (i == n-1) for (int g = b + 1; g <= G; g++) gs[g] = n;
  } else if (bid < bInit + bGb + bWp){
    int i = (bid - bInit - bGb)*256 + t;
    if (i >= WTOT) return;
    int l = i >> 14, r = i & 16383, nn = r >> 7, kk = r & 127;
    WtB[(size_t)l*WROWS*D + nn*D + kk] = f2b(Wg[(size_t)l*16384 + kk*128 + nn]);
  } else {
    int i = (bid - bInit - bGb - bWp)*256 + t;
    int wscTot = (WTOT >> 14)*16*128;     // L*16*128
    if (i >= wscTot) return;
    int l = i >> 11, r = i & 2047, j = r >> 7, k = r & 127;
    const float* wrow = Wg + (size_t)l*16384 + k*128;
    float s = 0.f;
    if (j < 8){
      const float* av = asrc + l*128 + j*16;
#pragma unroll
      for (int c = 0; c < 16; c++) s += wrow[j*16 + c] * av[c];
    } else {
      const float* av = adst + l*128 + (j - 8)*16;
#pragma unroll
      for (int c = 0; c < 16; c++) s += wrow[(j - 8)*16 + c] * av[c];
    }
    WtB[(size_t)l*WROWS*D + (128 + j)*D + k] = f2b(s);
  }
}

// ---------------- MFMA bf16 GEMM 256x144: B staged in LDS once per block ----------------
// 512 thr = 8 waves, 256 rows/block. B (36 KB) loaded to LDS once, reused by all
// waves via ds_read_b128; A fragments direct from global with BN+ReLU in registers;
// C stored directly to global (no LDS repack). One barrier total.
__global__ __launch_bounds__(512) void k_gemm(const ushort* __restrict__ hin,
                                              const ushort* __restrict__ WtB,
                                              ushort* __restrict__ xh,
                                              float* __restrict__ sc2,
                                              const float* __restrict__ bnsum,
                                              const float* __restrict__ gamma,
                                              const float* __restrict__ beta,
                                              int n, int first){
  __shared__ __align__(16) ushort wL[WROWS*136];   // 144 rows x (128+8 pad) = 39168 B
  __shared__ float sS[128], sB[128];
  int t = threadIdx.x;
  int wid = t >> 6, lane = t & 63, l15 = lane & 15, quad = lane >> 4;
  int n0 = blockIdx.x * 256;
  int rbase = wid*32;                  // wave-private row base (0..224)

  if (t < 128){
    float sc, sh;
    if (first){ sc = 1.f; sh = 0.f; }
    else {
      float s = 0.f, s2 = 0.f;
#pragma unroll 8
      for (int sl = 0; sl < NSLICE; sl++){
        s  += bnsum[sl*256 + t];
        s2 += bnsum[sl*256 + 128 + t];
      }
      float invn = 1.0f / (float)n;
      float mu = s * invn;
      float var = s2 * invn - mu*mu;
      sc = gamma[t] * rsqrtf(var + BN_EPS);
      sh = beta[t] - mu*sc;
    }
    sS[t] = sc; sB[t] = sh;
  }
  // stage B: 144 rows x 16 uint4 = 2304 uint4 over 512 threads
#pragma unroll
  for (int i = 0; i < 5; i++){
    int u = t + i*512;
    if (u < WROWS*16){
      int r = u >> 4, c8 = u & 15;
      *(uint4*)(wL + r*136 + c8*8) = *(const uint4*)(WtB + (size_t)r*D + c8*8);
    }
  }
  __syncthreads();   // the only barrier

  // A fragments: direct global load (16B, aligned), BN+ReLU in registers
  bfrag a[2][4];
#pragma unroll
  for (int mt = 0; mt < 2; mt++){
    int row = n0 + rbase + mt*16 + l15;
#pragma unroll
    for (int ks = 0; ks < 4; ks++){
      union { bfrag b; ushort us[8]; } in, ov;
      in.b = (bfrag){0,0,0,0,0,0,0,0};
      if (row < n) in.b = *(const bfrag*)(hin + (size_t)row*D + ks*32 + quad*8);
      int kb = ks*32 + quad*8;
#pragma unroll
      for (int j = 0; j < 8; j++){
        float f = bf2f(in.us[j])*sS[kb + j] + sB[kb + j];
        ov.us[j] = f2b(f > 0.f ? f : 0.f);
      }
      a[mt][ks] = ov.b;
    }
  }

  ffrag acc[2][9];
#pragma unroll
  for (int mt = 0; mt < 2; mt++)
#pragma unroll
    for (int nt = 0; nt < 9; nt++) acc[mt][nt] = (ffrag){0.f,0.f,0.f,0.f};

  // MFMA with LDS-resident B; nt==8 is the score-column tile
#pragma unroll
  for (int nt = 0; nt < 9; nt++){
#pragma unroll
    for (int ks = 0; ks < 4; ks++){
      bfrag b = *(const bfrag*)(wL + (nt*16 + l15)*136 + ks*32 + quad*8);
      acc[0][nt] = __builtin_amdgcn_mfma_f32_16x16x32_bf16(a[0][ks], b, acc[0][nt], 0, 0, 0);
      acc[1][nt] = __builtin_amdgcn_mfma_f32_16x16x32_bf16(a[1][ks], b, acc[1][nt], 0, 0, 0);
    }
  }

  // epilogue: direct stores, no LDS. C mapping: row = rbase+mt*16+quad*4+r, col = nt*16+l15.
#pragma unroll
  for (int mt = 0; mt < 2; mt++)
#pragma unroll
    for (int r = 0; r < 4; r++){
      int grow = n0 + rbase + mt*16 + quad*4 + r;
      if (grow < n){
        sc2[(size_t)grow*16 + l15] = acc[mt][8][r];
        ushort* xr = xh + (size_t)grow*D + l15;
#pragma unroll
        for (int nt = 0; nt < 8; nt++)
          xr[nt*16] = f2b(acc[mt][nt][r]);
      }
    }
}

// ---------------- wave-per-node aggregation (R10 measured-best form) ----------------
__global__ __launch_bounds__(1024) void k_agg(const uint* __restrict__ xh32,
                                              const float* __restrict__ sc2,
                                              const int* __restrict__ deg,
                                              const int* __restrict__ col,
                                              const float* __restrict__ bg,
                                              ushort* __restrict__ hout,
                                              float* __restrict__ bnsum, int n){
  int wv = threadIdx.x >> 6;
  int l  = threadIdx.x & 63;
  int hs = l & 7;
  int jc = l >> 3;          // score-role edge slot AND channel-role head
  int nid = blockIdx.x*16 + wv;

  float s0=0.f, s1=0.f, q0=0.f, q1=0.f;

  if (nid < n){
    const int* cb = col + nid*MAXDEG;
    int cnt = deg[nid];
    int idx[8];
#pragma unroll
    for (int jj = 0; jj < 8; jj++) idx[jj] = cb[jj];      // col pre-zeroed, unconditional
    float ad = sc2[nid*16 + 8 + hs];
    float as = sc2[nid*16 + hs];
    uint selfv = xh32[nid*64 + l];
    float av = sc2[idx[jc]*16 + hs];
    float xv0[8], xv1[8];
#pragma unroll
    for (int jj = 0; jj < 8; jj++){
      uint v = xh32[idx[jj]*64 + l];
      xv0[jj] = bf_lo(v); xv1[jj] = bf_hi(v);
    }
    if (cnt > MAXDEG) cnt = MAXDEG;
    int cc = cnt < 8 ? cnt : 8;
    float e0 = as + ad; e0 = e0 > 0.f ? e0 : NEG*e0;
    float m = e0, dnm = 1.f;
    float acc0 = bf_lo(selfv), acc1 = bf_hi(selfv);

    float e = -1e30f;
    if (jc < cc){ float ee = av + ad; e = ee > 0.f ? ee : NEG*ee; }
    float mc = e;
    mc = fmaxf(mc, __shfl_xor(mc, 8));
    mc = fmaxf(mc, __shfl_xor(mc, 16));
    mc = fmaxf(mc, __shfl_xor(mc, 32));
    float mn = fmaxf(m, mc);
    float rsc = __expf(m - mn);
    float w = (jc < cc) ? __expf(e - mn) : 0.f;
    float ws = w;
    ws += __shfl_xor(ws, 8);
    ws += __shfl_xor(ws, 16);
    ws += __shfl_xor(ws, 32);
    dnm = dnm*rsc + ws;
    m = mn;
    float rc = __shfl(rsc, jc);
    acc0 *= rc; acc1 *= rc;
#pragma unroll
    for (int jj = 0; jj < 8; jj++){
      float wj = __shfl(w, jj*8 + jc);
      acc0 += wj * xv0[jj];
      acc1 += wj * xv1[jj];
    }
    for (int c0 = 8; c0 < cnt; c0 += 8){
      int cc2 = cnt - c0; if (cc2 > 8) cc2 = 8;
#pragma unroll
      for (int jj = 0; jj < 8; jj++) idx[jj] = cb[c0 + jj];
      float av2 = sc2[idx[jc]*16 + hs];
#pragma unroll
      for (int jj = 0; jj < 8; jj++){
        uint v = xh32[idx[jj]*64 + l];
        xv0[jj] = bf_lo(v); xv1[jj] = bf_hi(v);
      }
      float e2 = -1e30f;
      if (jc < cc2){ float ee = av2 + ad; e2 = ee > 0.f ? ee : NEG*ee; }
      float mc2 = e2;
      mc2 = fmaxf(mc2, __shfl_xor(mc2, 8));
      mc2 = fmaxf(mc2, __shfl_xor(mc2, 16));
      mc2 = fmaxf(mc2, __shfl_xor(mc2, 32));
      float mn2 = fmaxf(m, mc2);
      float rsc2 = __expf(m - mn2);
      float w2 = (jc < cc2) ? __expf(e2 - mn2) : 0.f;
      float ws2 = w2;
      ws2 += __shfl_xor(ws2, 8);
      ws2 += __shfl_xor(ws2, 16);
      ws2 += __shfl_xor(ws2, 32);
      dnm = dnm*rsc2 + ws2;
      m = mn2;
      float rc2 = __shfl(rsc2, jc);
      acc0 *= rc2; acc1 *= rc2;
#pragma unroll
      for (int jj = 0; jj < 8; jj++){
        float wj = __shfl(w2, jj*8 + jc);
        acc0 += wj * xv0[jj];
        acc1 += wj * xv1[jj];
      }
    }
    float df = __shfl(dnm, jc);
    float inv = 1.0f / df;
    float b0 = bg[2*l], b1 = bg[2*l + 1];
    float o0 = acc0*inv + b0, o1 = acc1*inv + b1;
    uint p = ((uint)f2b(o0)) | (((uint)f2b(o1)) << 16);
    ((uint*)hout)[nid*64 + l] = p;
    s0 = o0; s1 = o1; q0 = o0*o0; q1 = o1*o1;
  }

  __shared__ float red[16][64][4];
  red[wv][l][0] = s0; red[wv][l][1] = s1; red[wv][l][2] = q0; red[wv][l][3] = q1;
  __syncthreads();
  if (wv == 0){
    float t0 = 0.f, t1 = 0.f, t2 = 0.f, t3 = 0.f;
#pragma unroll
    for (int k = 0; k < 16; k++){
      t0 += red[k][l][0]; t1 += red[k][l][1];
      t2 += red[k][l][2]; t3 += red[k][l][3];
    }
    float* bs = bnsum + (blockIdx.x & (NSLICE - 1))*256;
    atomicAdd(&bs[2*l],       t0);
    atomicAdd(&bs[2*l + 1],   t1);
    atomicAdd(&bs[128 + 2*l], t2);
    atomicAdd(&bs[129 + 2*l], t3);
  }
}

// ---------------- fused pool (BN+ReLU) + output heads ----------------
__global__ __launch_bounds__(128) void k_poolheads(const ushort* __restrict__ h,
                                                   const int* __restrict__ gs,
                                                   const float* __restrict__ bnsum,
                                                   const float* __restrict__ gamma,
                                                   const float* __restrict__ beta,
                                                   const float* __restrict__ hW1,
                                                   const float* __restrict__ hb1,
                                                   const float* __restrict__ hW2,
                                                   const float* __restrict__ hb2,
                                                   float* __restrict__ out, int n){
  int g = blockIdx.x;
  int t = threadIdx.x;
  __shared__ float sp[128];
  int st = gs[g], en = gs[g + 1];
  float sm = 0.f, s2 = 0.f;
#pragma unroll 8
  for (int sl = 0; sl < NSLICE; sl++){
    sm += bnsum[sl*256 + t];
    s2 += bnsum[sl*256 + 128 + t];
  }
  float invn = 1.0f / (float)n;
  float mu = sm * invn;
  float var = s2 * invn - mu*mu;
  float sc = gamma[t] * rsqrtf(var + BN_EPS);
  float sh = beta[t] - mu*sc;
  float s = 0.f;
  for (int r = st; r < en; r++){
    float v = bf2f(h[(size_t)r*D + t]) * sc + sh;
    s += v > 0.f ? v : 0.f;
  }
  float cnt = (float)(en - st);
  sp[t] = s / fmaxf(cnt, 1.0f);
  __syncthreads();
  int wv = t >> 6, m = t & 63;
  for (int k = wv; k < 3; k += 2){
    float acc = hb1[k*64 + m];
    const float* w = hW1 + k*8192 + m;      // [d][m], coalesced over m
#pragma unroll 16
    for (int d = 0; d < 128; d++) acc += sp[d] * w[d*64];
    float val = fmaxf(acc, 0.f) * hW2[k*64 + m];
#pragma unroll
    for (int off = 32; off; off >>= 1) val += __shfl_down(val, off);
    if (m == 0) out[(size_t)g*3 + k] = val + hb2[k];
  }
}

// ---------------- launch ----------------
extern "C" void kernel_launch(void* const* d_in, const int* in_sizes, int n_in,
                              void* d_out, int out_size, void* d_ws, size_t ws_size,
                              hipStream_t stream){
  const float* x    = (const float*)d_in[0];
  const int*   ei   = (const int*)d_in[1];
  const int*   batch= (const int*)d_in[2];
  const float* Wp   = (const float*)d_in[3];
  const float* bp   = (const float*)d_in[4];
  const float* Wg   = (const float*)d_in[5];
  const float* asrc = (const float*)d_in[6];
  const float* adst = (const float*)d_in[7];
  const float* bg   = (const float*)d_in[8];
  const float* gamma= (const float*)d_in[9];
  const float* beta = (const float*)d_in[10];
  const float* hW1  = (const float*)d_in[11];
  const float* hb1  = (const float*)d_in[12];
  const float* hW2  = (const float*)d_in[13];
  const float* hb2  = (const float*)d_in[14];
  float* out = (float*)d_out;

  const int E = in_sizes[1] / 2;
  const int N = in_sizes[2];
  const int G = out_size / 3;
  const int WTOT = in_sizes[5];           // L*D*D
  const int L = WTOT / 16384;

  char* w = (char*)d_ws;
  auto alloc = [&](size_t bytes){ char* p = w; w += (bytes + 255) & ~(size_t)255; return p; };
  ushort* h     = (ushort*)alloc((size_t)N*D*2);
  ushort* xh    = (ushort*)alloc((size_t)N*D*2);
  float* sc2    = (float*)alloc((size_t)N*16*4);
  // zero-initialized region: deg, col, bnsumL contiguous
  int*   deg    = (int*)  alloc((size_t)N*4);
  int*   col    = (int*)  alloc(((size_t)N*MAXDEG + 64)*4);
  float* bnsumL = (float*)alloc((size_t)4*NSLICE*256*4);   // per-layer slices
  char*  zend   = w;
  int*   gs     = (int*)  alloc((size_t)(G + 1)*4);
  ushort* WtB   = (ushort*)alloc((size_t)L*WROWS*D*2);

  hipMemsetAsync(deg, 0, (size_t)(zend - (char*)deg), stream);
  k_scatter<<<(E + 255)/256, 256, 0, stream>>>(ei, deg, col, E);

  const int bInit = (N*32 + 255)/256;
  const int bGb   = (N + 255)/256;
  const int bWp   = (WTOT + 255)/256;
  const int bWsc  = (WTOT/8 + 255)/256;   // L*16*128 elements
  k_setup<<<bInit + bGb + bWp + bWsc, 256, 0, stream>>>(
      x, Wp, bp, h, batch, gs, Wg, asrc, adst, WtB,
      N, G, WTOT, bInit, bGb, bWp);

  for (int l = 0; l < 4; l++){
    float* bnPrev = bnsumL + (size_t)(l - 1)*NSLICE*256;   // unused when l==0
    float* bnCur  = bnsumL + (size_t)l*NSLICE*256;
    k_gemm<<<(N + 255)/256, 512, 0, stream>>>(h, WtB + (size_t)l*WROWS*D, xh, sc2,
                                              l == 0 ? bnCur : bnPrev,
                                              gamma + l*D, beta + l*D, N, l == 0);
    k_agg<<<(N + 15)/16, 1024, 0, stream>>>((const uint*)xh, sc2, deg, col,
                                            bg + l*D, h, bnCur, N);
  }

  k_poolheads<<<G, 128, 0, stream>>>(h, gs, bnsumL + (size_t)3*NSLICE*256,
                                     gamma + 3*D, beta + 3*D,
                                     hW1, hb1, hW2, hb2, out, N);
}